// Round 7
// baseline (164.058 us; speedup 1.0000x reference)
//
#include <hip/hip_runtime.h>

// ---------------------------------------------------------------------------
// All float tensors in this dataset are float32 (reference dtypes; confirmed
// by the harness threshold being exactly 2% relative with no bf16 floor).
// Inputs: h f32[1024*128], adj i32[1024*1024], W_l/W_r/W_v f32[128*128],
// a f32[32], ln_g f32[128], ln_b f32[128]. Output f32[1024*128].
// NOTE: an exactly-max|ref| absmax (4.28125) means the ref-argmax region of
// d_out was never written — rounds 1-6 wrote u16 into an f32 buffer.
// ---------------------------------------------------------------------------

// K1: projections Wlh = h@W_l, Wrh = h@W_r, V = h@W_v.
// grid 1024 x 128: block b = node, thread t = output column; W reads coalesced.
__global__ __launch_bounds__(128) void k1_proj(
        const float* __restrict__ h,  const float* __restrict__ Wl,
        const float* __restrict__ Wr, const float* __restrict__ Wv,
        float* __restrict__ Wlh, float* __restrict__ Wrh, float* __restrict__ V) {
    __shared__ float hs[128];
    int b = blockIdx.x, t = threadIdx.x;
    hs[t] = h[b * 128 + t];
    __syncthreads();
    float al = 0.f, ar = 0.f, av = 0.f;
    #pragma unroll 4
    for (int k = 0; k < 128; k++) {
        float hk = hs[k];
        al += hk * Wl[k * 128 + t];
        ar += hk * Wr[k * 128 + t];
        av += hk * Wv[k * 128 + t];
    }
    Wlh[b * 128 + t] = al;
    Wrh[b * 128 + t] = ar;
    V[b * 128 + t]   = av;
}

// K2 (identifier-named): fused GATv2 per node i.
// scores e[h][j] -> masked softmax over j -> aggregate alpha @ V ->
// LayerNorm -> ReLU.  grid 1024 x 256. LDS ~18 KB.
__global__ __launch_bounds__(256) void GATv2Layer_84447646974220_kernel(
        const float* __restrict__ Wlh, const float* __restrict__ Wrh,
        const float* __restrict__ V,   const int* __restrict__ adj,
        const float* __restrict__ a_,  const float* __restrict__ g_,
        const float* __restrict__ b_,  float* __restrict__ out) {
    __shared__ __align__(16) float wl_s[128];
    __shared__ __align__(16) float a_s[32];
    __shared__ float e_s[4][1024];     // [head][j], becomes p after exp
    __shared__ float red[4][8];        // reduction scratch
    __shared__ float agg_s[2][128];    // [j-segment][col]
    __shared__ float lr_s[4];          // 1/l per head

    const int i = blockIdx.x, t = threadIdx.x;
    const int lane = t & 63, w = t >> 6;

    if (t < 128) wl_s[t] = Wlh[i * 128 + t];
    if (t < 32)  a_s[t]  = a_[t];
    __syncthreads();

    // ---- phase A: scores + per-thread max (float4 row reads) ----
    float mx0 = -1e30f, mx1 = -1e30f, mx2 = -1e30f, mx3 = -1e30f;
    const float4* wl4 = (const float4*)wl_s;
    const float4* a4  = (const float4*)a_s;
    for (int jj = 0; jj < 4; jj++) {
        int j = jj * 256 + t;
        int m = adj[i * 1024 + j];
        const float4* wr4 = (const float4*)(Wrh + (size_t)j * 128);
        float e[4];
        #pragma unroll
        for (int hh = 0; hh < 4; hh++) {
            float acc = 0.f;
            #pragma unroll
            for (int d4 = 0; d4 < 8; d4++) {
                float4 wv = wr4[hh * 8 + d4];
                float4 lv = wl4[hh * 8 + d4];
                float4 av = a4[d4];
                float s;
                s = lv.x + wv.x; s = (s >= 0.f) ? s : 0.2f * s; acc += s * av.x;
                s = lv.y + wv.y; s = (s >= 0.f) ? s : 0.2f * s; acc += s * av.y;
                s = lv.z + wv.z; s = (s >= 0.f) ? s : 0.2f * s; acc += s * av.z;
                s = lv.w + wv.w; s = (s >= 0.f) ? s : 0.2f * s; acc += s * av.w;
            }
            e[hh] = m ? acc : -1e30f;
            e_s[hh][j] = e[hh];
        }
        mx0 = fmaxf(mx0, e[0]); mx1 = fmaxf(mx1, e[1]);
        mx2 = fmaxf(mx2, e[2]); mx3 = fmaxf(mx3, e[3]);
    }
    {
        float m0 = mx0, m1 = mx1, m2 = mx2, m3 = mx3;
        for (int off = 32; off > 0; off >>= 1) {
            m0 = fmaxf(m0, __shfl_xor(m0, off));
            m1 = fmaxf(m1, __shfl_xor(m1, off));
            m2 = fmaxf(m2, __shfl_xor(m2, off));
            m3 = fmaxf(m3, __shfl_xor(m3, off));
        }
        if (lane == 0) {
            red[0][w] = m0; red[1][w] = m1; red[2][w] = m2; red[3][w] = m3;
        }
    }
    __syncthreads();
    float Mh[4];
    #pragma unroll
    for (int hh = 0; hh < 4; hh++)
        Mh[hh] = fmaxf(fmaxf(red[hh][0], red[hh][1]),
                       fmaxf(red[hh][2], red[hh][3]));

    // ---- phase B: exp + sum ----
    float sm0 = 0.f, sm1 = 0.f, sm2 = 0.f, sm3 = 0.f;
    for (int jj = 0; jj < 4; jj++) {
        int j = jj * 256 + t;
        float p0 = expf(e_s[0][j] - Mh[0]);
        float p1 = expf(e_s[1][j] - Mh[1]);
        float p2 = expf(e_s[2][j] - Mh[2]);
        float p3 = expf(e_s[3][j] - Mh[3]);
        e_s[0][j] = p0; sm0 += p0;
        e_s[1][j] = p1; sm1 += p1;
        e_s[2][j] = p2; sm2 += p2;
        e_s[3][j] = p3; sm3 += p3;
    }
    {
        float l0 = sm0, l1 = sm1, l2 = sm2, l3 = sm3;
        for (int off = 32; off > 0; off >>= 1) {
            l0 += __shfl_xor(l0, off);
            l1 += __shfl_xor(l1, off);
            l2 += __shfl_xor(l2, off);
            l3 += __shfl_xor(l3, off);
        }
        if (lane == 0) {
            red[0][4 + w] = l0; red[1][4 + w] = l1;
            red[2][4 + w] = l2; red[3][4 + w] = l3;
        }
    }
    __syncthreads();
    if (t < 4) {
        float l = red[t][4] + red[t][5] + red[t][6] + red[t][7];
        lr_s[t] = 1.0f / l;
    }
    __syncthreads();

    // ---- phase C: agg[c] = sum_j p[h(c)][j] * V[j][c] ----
    {
        const int c = t & 127, seg = t >> 7, hh = c >> 5;
        float acc = 0.f;
        int j0 = seg * 512;
        for (int j = j0; j < j0 + 512; j++)
            acc += e_s[hh][j] * V[(size_t)j * 128 + c];
        agg_s[seg][c] = acc;
    }
    __syncthreads();

    // ---- phase D: LayerNorm + ReLU over 128 cols (threads 0..127) ----
    if (t < 128) {
        float x = (agg_s[0][t] + agg_s[1][t]) * lr_s[t >> 5];
        float s1 = x, s2 = x * x;
        for (int off = 32; off > 0; off >>= 1) {
            s1 += __shfl_xor(s1, off);
            s2 += __shfl_xor(s2, off);
        }
        if (lane == 0) { red[0][w] = s1; red[1][w] = s2; }
    }
    __syncthreads();
    if (t < 128) {
        float x = (agg_s[0][t] + agg_s[1][t]) * lr_s[t >> 5];
        float s1 = red[0][0] + red[0][1];
        float s2 = red[1][0] + red[1][1];
        float mean = s1 * (1.f / 128.f);
        float var  = s2 * (1.f / 128.f) - mean * mean;
        float rs   = rsqrtf(var + 1e-5f);
        float y = (x - mean) * rs * g_[t] + b_[t];
        out[(size_t)i * 128 + t] = fmaxf(y, 0.f);
    }
}

// ---------------------------------------------------------------------------
extern "C" void kernel_launch(void* const* d_in, const int* in_sizes, int n_in,
                              void* d_out, int out_size, void* d_ws, size_t ws_size,
                              hipStream_t stream) {
    const float* h   = (const float*)d_in[0];
    const int*   adj = (const int*)d_in[1];
    const float* Wl  = (const float*)d_in[2];
    const float* Wr  = (const float*)d_in[3];
    const float* Wv  = (const float*)d_in[4];
    const float* a_  = (const float*)d_in[5];
    const float* g_  = (const float*)d_in[6];
    const float* b_  = (const float*)d_in[7];
    float* out = (float*)d_out;

    char* ws = (char*)d_ws;
    float* Wlh = (float*)(ws);                 // 1024*128 f32 = 512 KB
    float* Wrh = (float*)(ws + 524288);        // 512 KB
    float* V   = (float*)(ws + 1048576);       // 512 KB

    k1_proj<<<1024, 128, 0, stream>>>(h, Wl, Wr, Wv, Wlh, Wrh, V);
    GATv2Layer_84447646974220_kernel<<<1024, 256, 0, stream>>>(
        Wlh, Wrh, V, adj, a_, g_, b_, out);
}

// Round 8
// 98.257 us; speedup vs baseline: 1.6697x; 1.6697x over previous
//
#include <hip/hip_runtime.h>
#include <cstdint>

typedef _Float16 f16;
typedef _Float16 f16x2 __attribute__((ext_vector_type(2)));
typedef _Float16 f16x4 __attribute__((ext_vector_type(4)));
typedef _Float16 f16x8 __attribute__((ext_vector_type(8)));
typedef float    f32x4 __attribute__((ext_vector_type(4)));
typedef unsigned short u16;
typedef unsigned int   u32;

#define LOG2E 1.44269504088896340736f

__device__ __forceinline__ f16x2 habs2(f16x2 v) {
    union { f16x2 h; u32 u; } x; x.h = v; x.u &= 0x7FFF7FFFu; return x.h;
}
#if __has_builtin(__builtin_amdgcn_fdot2)
__device__ __forceinline__ float fdot2f(f16x2 a, f16x2 b, float c) {
    return __builtin_amdgcn_fdot2(a, b, c, false);
}
#else
__device__ __forceinline__ float fdot2f(f16x2 a, f16x2 b, float c) {
    return c + (float)a.x * (float)b.x + (float)a.y * (float)b.y;
}
#endif
#if __has_builtin(__builtin_amdgcn_exp2f)
#define EXP2F __builtin_amdgcn_exp2f
#else
#define EXP2F exp2f
#endif

// ---------------------------------------------------------------------------
// K0: transpose W_l/W_r/W_v (f32 [128k][128o]) -> WT f16 [w][o][k]; h -> f16.
// grid 512 x 64.
// ---------------------------------------------------------------------------
__global__ __launch_bounds__(64) void k0_prep(
        const float* __restrict__ Wl, const float* __restrict__ Wr,
        const float* __restrict__ Wv, const float* __restrict__ h,
        f16* __restrict__ WT, f16* __restrict__ h16) {
    int b = blockIdx.x, t = threadIdx.x;
    if (b < 384) {
        int w = b >> 7, o = b & 127;
        const float* W = (w == 0) ? Wl : ((w == 1) ? Wr : Wv);
        f16* dst = WT + (w * 128 + o) * 128;
        #pragma unroll
        for (int kk = 0; kk < 2; kk++) {
            int k = t + kk * 64;
            dst[k] = (f16)W[k * 128 + o];
        }
    } else {
        int r0 = (b - 384) * 8;              // 8 rows of h = 1024 elems
        const float* src = h + r0 * 128;
        f16* dst = h16 + r0 * 128;
        int base = t * 16;
        #pragma unroll
        for (int e = 0; e < 16; e++) dst[base + e] = (f16)src[base + e];
    }
}

// ---------------------------------------------------------------------------
// K1: projections via v_dot2_f32_f16. grid 256 x 384; block = 4 nodes;
// thread t -> (t>>7 selects W_l/W_r/W_v, t&127 is the output column).
// Outputs:
//   Wlh f16 [j][128]                 (o = h*32+d)
//   WrL f16 [4h][8c][1024 j][4 l]    (d = 4c+l; coalesced K2 phase-1 loads)
//   VL  f16 [4h][32 d][1024 j]       (MFMA B-frag: 8 contiguous j at fixed d)
// ---------------------------------------------------------------------------
__global__ __launch_bounds__(384) void k1_proj(
        const f16* __restrict__ WT, const f16* __restrict__ h16,
        f16* __restrict__ Wlh, f16* __restrict__ WrL, f16* __restrict__ VL) {
    int t = threadIdx.x;
    int i0 = blockIdx.x * 4;
    int wsel = t >> 7, col = t & 127;

    f16x2 w2[64];
    {
        const f16x2* src = (const f16x2*)(WT + t * 128);
        #pragma unroll
        for (int c2 = 0; c2 < 64; c2++) w2[c2] = src[c2];
    }
    #pragma unroll
    for (int i = 0; i < 4; i++) {
        int j = i0 + i;
        const f16x2* hr = (const f16x2*)(h16 + j * 128);
        float acc = 0.f;
        #pragma unroll
        for (int c2 = 0; c2 < 64; c2++) acc = fdot2f(hr[c2], w2[c2], acc);
        f16 hv = (f16)acc;
        if (wsel == 0) {
            Wlh[j * 128 + col] = hv;
        } else if (wsel == 1) {
            int hh = col >> 5, dd = col & 31, c = dd >> 2, l = dd & 3;
            WrL[((hh * 8 + c) * 1024 + j) * 4 + l] = hv;
        } else {
            int hh = col >> 5, dd = col & 31;
            VL[(hh * 32 + dd) * 1024 + j] = hv;
        }
    }
}

// ---------------------------------------------------------------------------
// K2: fused GATv2 attention + MFMA aggregation + LayerNorm + ReLU.
// grid 256 x 512. Block = 4 nodes i. 8 waves: wave w -> (head hh = w&3,
// j-half = w>>2). LDS 37 KB. WrL/VL read from global (L2-resident).
// lrelu identity: a·lrelu(t) = (0.6a)·t + (0.4a)·|t|.
// ---------------------------------------------------------------------------
__global__ __launch_bounds__(512) void GATv2Layer_84447646974220_kernel(
        const f16* __restrict__ Wlh, const f16* __restrict__ WrL,
        const f16* __restrict__ VL,  const int* __restrict__ adj,
        const float* __restrict__ a_, const float* __restrict__ ln_g,
        const float* __restrict__ ln_b, float* __restrict__ out) {

    __shared__ __align__(16) f16 ep[4][4][1024];   // [head][row][j]  32768 B
    __shared__ float aggS[2][4][128];              // [half][row][col] 4096 B
    __shared__ float redM[2][4][4];                // [half][head][row]
    __shared__ float redS[2][4][4];

    const int t    = threadIdx.x;
    const int w    = t >> 6;        // 0..7
    const int lane = t & 63;
    const int hh   = w & 3;         // head
    const int half = w >> 2;        // j-half (0: j<512, 1: j>=512)
    const int i0   = blockIdx.x * 4;

    // per-wave constants: p2 = 0.6*a, q2 = 0.4*a (f16 pairs), Wl head-slices
    f16x2 p2[16], q2[16];
    #pragma unroll
    for (int d2 = 0; d2 < 16; d2++) {
        float a0 = a_[2 * d2], a1 = a_[2 * d2 + 1];
        f16x2 p; p.x = (f16)(0.6f * a0); p.y = (f16)(0.6f * a1);
        f16x2 q; q.x = (f16)(0.4f * a0); q.y = (f16)(0.4f * a1);
        p2[d2] = p; q2[d2] = q;
    }
    f16x2 wl2[4][16];
    #pragma unroll
    for (int ii = 0; ii < 4; ii++) {
        const f16x2* src = (const f16x2*)(Wlh + (i0 + ii) * 128 + hh * 32);
        #pragma unroll
        for (int c2 = 0; c2 < 16; c2++) wl2[ii][c2] = src[c2];
    }

    // ---- phase 1: scores e[i][j] for this wave's (head, j-half) ----
    float maxE[4];
    #pragma unroll
    for (int ii = 0; ii < 4; ii++) maxE[ii] = -__builtin_inff();

    #pragma unroll 1
    for (int jb = 0; jb < 8; jb++) {
        int j = half * 512 + jb * 64 + lane;
        f16x4 wr[8];
        #pragma unroll
        for (int c = 0; c < 8; c++)
            wr[c] = *(const f16x4*)(WrL + ((hh * 8 + c) * 1024 + j) * 4);
        int am[4];
        #pragma unroll
        for (int ii = 0; ii < 4; ii++) am[ii] = adj[(i0 + ii) * 1024 + j];

        float e[4] = {0.f, 0.f, 0.f, 0.f};
        #pragma unroll
        for (int c = 0; c < 8; c++) {
            #pragma unroll
            for (int ii = 0; ii < 4; ii++) {
                f16x2 t0 = wl2[ii][2 * c]     + wr[c].lo;
                f16x2 t1 = wl2[ii][2 * c + 1] + wr[c].hi;
                e[ii] = fdot2f(p2[2 * c],     t0, e[ii]);
                e[ii] = fdot2f(q2[2 * c],     habs2(t0), e[ii]);
                e[ii] = fdot2f(p2[2 * c + 1], t1, e[ii]);
                e[ii] = fdot2f(q2[2 * c + 1], habs2(t1), e[ii]);
            }
        }
        #pragma unroll
        for (int ii = 0; ii < 4; ii++) {
            float v = am[ii] ? e[ii] : -__builtin_inff();
            maxE[ii] = fmaxf(maxE[ii], v);
            ep[hh][ii][j] = (f16)v;
        }
    }

    // ---- phase 2: softmax (cross-half max/sum through LDS) ----
    #pragma unroll
    for (int ii = 0; ii < 4; ii++) {
        float M = maxE[ii];
        #pragma unroll
        for (int off = 32; off > 0; off >>= 1) M = fmaxf(M, __shfl_xor(M, off));
        if (lane == 0) redM[half][hh][ii] = M;
    }
    __syncthreads();

    #pragma unroll
    for (int ii = 0; ii < 4; ii++) {
        float M = fmaxf(redM[0][hh][ii], redM[1][hh][ii]);
        f16x8 v0 = *(f16x8*)&ep[hh][ii][half * 512 + lane * 8];
        float pb[8], l = 0.f;
        #pragma unroll
        for (int e = 0; e < 8; e++) pb[e] = EXP2F(((float)v0[e] - M) * LOG2E);
        #pragma unroll
        for (int e = 0; e < 8; e++) { v0[e] = (f16)pb[e]; l += pb[e]; }
        *(f16x8*)&ep[hh][ii][half * 512 + lane * 8] = v0;
        #pragma unroll
        for (int off = 32; off > 0; off >>= 1) l += __shfl_xor(l, off);
        if (lane == 0) redS[half][hh][ii] = l;
    }
    __syncthreads();

    float lr[4];
    #pragma unroll
    for (int ii = 0; ii < 4; ii++)
        lr[ii] = 1.0f / (redS[0][hh][ii] + redS[1][hh][ii]);

    // ---- phase 3: agg = p @ V via MFMA ----
    // A-frag: A[m=lane&15][k=(lane>>4)*8+jj]; rows 4..15 duplicate rows 0..3
    // (m3 = lane&3) — garbage C-rows discarded. B-frag: B[k][n=lane&15] from
    // VL[d=n][j=k] (contiguous j). C/D: col=lane&15, row=(lane>>4)*4+reg.
    f32x4 acc0 = {0.f, 0.f, 0.f, 0.f}, acc1 = {0.f, 0.f, 0.f, 0.f};
    const int q8  = (lane >> 4) << 3;
    const int m3  = lane & 3;
    const int n15 = lane & 15;

    #pragma unroll 1
    for (int jt4 = 0; jt4 < 4; jt4++) {
        int jt = half * 4 + jt4;
        #pragma unroll
        for (int kk = 0; kk < 4; kk++) {
            int ko = jt * 128 + kk * 32 + q8;
            f16x8 af = *(const f16x8*)&ep[hh][m3][ko];
            f16x8 b0 = *(const f16x8*)(VL + (hh * 32 + n15) * 1024 + ko);
            f16x8 b1 = *(const f16x8*)(VL + (hh * 32 + 16 + n15) * 1024 + ko);
            acc0 = __builtin_amdgcn_mfma_f32_16x16x32_f16(af, b0, acc0, 0, 0, 0);
            acc1 = __builtin_amdgcn_mfma_f32_16x16x32_f16(af, b1, acc1, 0, 0, 0);
        }
    }

    if (lane < 16) {
        #pragma unroll
        for (int r = 0; r < 4; r++) {
            aggS[half][r][hh * 32 + lane]      = acc0[r] * lr[r];
            aggS[half][r][hh * 32 + 16 + lane] = acc1[r] * lr[r];
        }
    }
    __syncthreads();

    // ---- phase 4: LayerNorm + ReLU (waves 0..3, one node-row each) ----
    if (w < 4) {
        float x0 = aggS[0][w][lane]      + aggS[1][w][lane];
        float x1 = aggS[0][w][lane + 64] + aggS[1][w][lane + 64];
        float s = x0 + x1, sq = x0 * x0 + x1 * x1;
        #pragma unroll
        for (int off = 32; off > 0; off >>= 1) {
            s  += __shfl_xor(s, off);
            sq += __shfl_xor(sq, off);
        }
        float mean = s * (1.f / 128.f);
        float var  = sq * (1.f / 128.f) - mean * mean;
        float rs   = rsqrtf(var + 1e-5f);
        float y0 = fmaxf((x0 - mean) * rs * ln_g[lane]      + ln_b[lane],      0.f);
        float y1 = fmaxf((x1 - mean) * rs * ln_g[lane + 64] + ln_b[lane + 64], 0.f);
        out[(i0 + w) * 128 + lane]      = y0;
        out[(i0 + w) * 128 + 64 + lane] = y1;
    }
}

// ---------------------------------------------------------------------------
extern "C" void kernel_launch(void* const* d_in, const int* in_sizes, int n_in,
                              void* d_out, int out_size, void* d_ws, size_t ws_size,
                              hipStream_t stream) {
    const float* h   = (const float*)d_in[0];
    const int*   adj = (const int*)d_in[1];
    const float* Wl  = (const float*)d_in[2];
    const float* Wr  = (const float*)d_in[3];
    const float* Wv  = (const float*)d_in[4];
    const float* a_  = (const float*)d_in[5];
    const float* g_  = (const float*)d_in[6];
    const float* b_  = (const float*)d_in[7];
    float* out = (float*)d_out;

    char* ws = (char*)d_ws;
    f16* WT  = (f16*)(ws);                 // 3*128*128 f16   =  98304 B
    f16* h16 = (f16*)(ws + 98304);         // 1024*128 f16    = 262144 B
    f16* Wlh = (f16*)(ws + 360448);        // 1024*128 f16    = 262144 B
    f16* WrL = (f16*)(ws + 622592);        // [4][8][1024][4] = 262144 B
    f16* VL  = (f16*)(ws + 884736);        // [4][32][1024]   = 262144 B

    k0_prep<<<512, 64, 0, stream>>>(Wl, Wr, Wv, h, WT, h16);
    k1_proj<<<256, 384, 0, stream>>>(WT, h16, Wlh, WrL, VL);
    GATv2Layer_84447646974220_kernel<<<256, 512, 0, stream>>>(
        Wlh, WrL, VL, adj, a_, g_, b_, out);
}